// Round 17
// baseline (95.663 us; speedup 1.0000x reference)
//
#include <hip/hip_runtime.h>
#include <hip/hip_bf16.h>

typedef __attribute__((ext_vector_type(8))) short bf16x8s;   // 8 bf16 as shorts (MFMA frag)
typedef __attribute__((ext_vector_type(4))) float f32x4;
typedef __attribute__((ext_vector_type(16))) float f32x16;
typedef __attribute__((ext_vector_type(4))) __bf16 bf16x4;
typedef __attribute__((ext_vector_type(8))) __bf16 bf16x8;

typedef const __attribute__((address_space(1))) void gvoid_t;
typedef __attribute__((address_space(3))) void lvoid_t;

constexpr int Bc = 2, Tc = 2048, Dc = 1024, Hc = 16, HDc = 64;
constexpr int Mc = Bc * Tc;  // 4096

// ---------------- fused fp32 -> bf16 convert: x (4096 blocks) + 4 weights (4096) ----
__global__ void cvt_all(const float* __restrict__ x,
                        const float* __restrict__ wq, const float* __restrict__ wk,
                        const float* __restrict__ wv, const float* __restrict__ wp,
                        __bf16* __restrict__ xb, __bf16* __restrict__ wb) {
  const int bid = blockIdx.x;
  const float* src;
  __bf16* dst;
  int i;
  if (bid < 4096) {
    src = x; dst = xb; i = (bid * 256 + threadIdx.x) * 4;
  } else {
    const int r = bid - 4096;
    const int w = r >> 10;
    src = (w == 0) ? wq : (w == 1) ? wk : (w == 2) ? wv : wp;
    dst = wb + (size_t)w * (Dc * Dc);
    i = ((r & 1023) * 256 + threadIdx.x) * 4;
  }
  float4 v = *(const float4*)(src + i);
  bf16x4 o;
  o[0] = (__bf16)v.x; o[1] = (__bf16)v.y; o[2] = (__bf16)v.z; o[3] = (__bf16)v.w;
  *(bf16x4*)(dst + i) = o;
}

// ---------------- QKV GEMM (fused-z, v2): counted vmcnt + L2-resident B ------------
// 256 blocks x 512 thr (8 waves of 32 rows x 64 cols); one block = 128x128 tile of
// Q, K, AND V (A staged once per 3 B-tiles). XCD map: bcol = (lid&7)*128 -> each
// XCD owns ONE 128-col slice of all 3 W's (768KB, L2-resident); A rows stream.
// K-loop: STAGE(s+1) -> vmcnt(8) [s landed, s+1 in flight] -> barrier -> compute(s)
// -> barrier. Stage latency spans the whole compute phase (T4). T2 XOR swizzle on
// A/B LDS (pre-swizzled source + swizzled read). Epilogues: RoPE+scale / RoPE / V^T.
__launch_bounds__(512, 2)
__global__ void gemm_qkv(const __bf16* __restrict__ A,
                         const __bf16* __restrict__ W,
                         __bf16* __restrict__ outb,
                         __bf16* __restrict__ vtout,
                         const float* __restrict__ cbt,
                         const float* __restrict__ sbt) {
  __shared__ __bf16 Albuf[2][128 * 64];      // 32KB
  __shared__ __bf16 Bbuf[2][3][128 * 64];    // 96KB
  const int tid = threadIdx.x;
  const int lane = tid & 63, wid = tid >> 6;
  const int wr = wid >> 1, wc = wid & 1;     // wave: rows [wr*32,+32), cols [wc*64,+64)
  const int lr = lane & 15, lg = lane >> 4;
  const int lid = blockIdx.x + 8 * blockIdx.y;   // grid (8,32)
  const int brow = (lid >> 3) * 128;             // 32 brows: A streams through L2
  const int bcol = (lid & 7) * 128;              // per-XCD B slice: 768KB L2-resident

  f32x4 acc[3][2][4] = {};   // [z][m: 16-row grp][n: 16-col grp]

  const char* Ag = (const char*)(A + (size_t)brow * Dc);
  const char* Bg = (const char*)(W + (size_t)bcol * Dc);
  const int r0s = tid >> 3;                        // row within 64-row chunk
  const int scol = (((tid & 7) ^ (r0s & 7)) << 4); // pre-swizzled source col byte
  const int lr7 = lr & 7;                          // read-side row key

#define STAGE(K0, BUF)                                                                    \
  do {                                                                                    \
    _Pragma("unroll")                                                                     \
    for (int i_ = 0; i_ < 2; ++i_) {                                                      \
      __builtin_amdgcn_global_load_lds(                                                   \
          (gvoid_t*)(Ag + (size_t)(i_ * 64 + r0s) * (Dc * 2) + (K0)*2 + scol),            \
          (lvoid_t*)((char*)Albuf[BUF] + i_ * 8192 + wid * 1024), 16, 0, 0);              \
      _Pragma("unroll")                                                                   \
      for (int z_ = 0; z_ < 3; ++z_)                                                      \
        __builtin_amdgcn_global_load_lds(                                                 \
            (gvoid_t*)(Bg + (size_t)z_ * (Dc * Dc * 2) +                                  \
                       (size_t)(i_ * 64 + r0s) * (Dc * 2) + (K0)*2 + scol),               \
            (lvoid_t*)((char*)Bbuf[BUF][z_] + i_ * 8192 + wid * 1024), 16, 0, 0);         \
    }                                                                                     \
  } while (0)

  STAGE(0, 0);

  for (int s = 0; s < 16; ++s) {
    if (s + 1 < 16) {
      STAGE((s + 1) * 64, (s + 1) & 1);
      asm volatile("s_waitcnt vmcnt(8)" ::: "memory");  // tile s landed; s+1 in flight
    } else {
      asm volatile("s_waitcnt vmcnt(0)" ::: "memory");
    }
    __builtin_amdgcn_sched_barrier(0);
    __builtin_amdgcn_s_barrier();        // tile s visible to all waves
    __builtin_amdgcn_sched_barrier(0);

    const char* Al = (const char*)Albuf[s & 1];
    const char* Bl0 = (const char*)Bbuf[s & 1][0];
#pragma unroll
    for (int kk = 0; kk < 2; ++kk) {
      const int sw = ((kk * 4 + lg) ^ lr7) << 4;   // swizzled 16B slot
      bf16x8s af[2];
#pragma unroll
      for (int m = 0; m < 2; ++m)
        af[m] = *(const bf16x8s*)(Al + (wr * 32 + m * 16 + lr) * 128 + sw);
#pragma unroll
      for (int z = 0; z < 3; ++z) {
        const char* Bl = Bl0 + z * (128 * 64 * 2);
        bf16x8s bfv[4];
#pragma unroll
        for (int n = 0; n < 4; ++n)
          bfv[n] = *(const bf16x8s*)(Bl + (wc * 64 + n * 16 + lr) * 128 + sw);
        __builtin_amdgcn_s_setprio(1);
#pragma unroll
        for (int m = 0; m < 2; ++m)
#pragma unroll
          for (int n = 0; n < 4; ++n)
            acc[z][m][n] =
                __builtin_amdgcn_mfma_f32_16x16x32_bf16(af[m], bfv[n], acc[z][m][n], 0, 0, 0);
        __builtin_amdgcn_s_setprio(0);
      }
    }
    __builtin_amdgcn_sched_barrier(0);
    __builtin_amdgcn_s_barrier();        // all waves done reading buf[s&1]
    __builtin_amdgcn_sched_barrier(0);
  }
#undef STAGE

  // ---- epilogue: z=0 (Q: RoPE+scale), z=1 (K: RoPE) — scatter to [B,H,T,HD] ----
  const int h = (bcol >> 6) + wc;
#pragma unroll
  for (int z = 0; z < 2; ++z) {
    const float scl = (z == 0) ? 0.18033688011112042f : 1.0f;  // (1/8)*log2(e)
    __bf16* dst = outb + (size_t)z * ((size_t)Mc * Dc);
#pragma unroll
    for (int m = 0; m < 2; ++m) {
#pragma unroll
      for (int j = 0; j < 4; ++j) {
        const int gm = brow + wr * 32 + m * 16 + lg * 4 + j;
        const int bb = gm >> 11, t = gm & (Tc - 1);
        const float* cbase = cbt + (size_t)gm * HDc;
        const float* sbase = sbt + (size_t)gm * HDc;
#pragma unroll
        for (int n = 0; n < 2; ++n) {
          const int i = n * 16 + lr;
          const float c0 = cbase[i], s0 = sbase[i];   // cos[i+32]==cos[i]
          const float v0 = acc[z][m][n][j], v1 = acc[z][m][n + 2][j];
          acc[z][m][n][j]     = (v0 * c0 - v1 * s0) * scl;
          acc[z][m][n + 2][j] = (v1 * c0 + v0 * s0) * scl;
        }
        __bf16* rowp = dst + (((size_t)bb * Hc + h) * Tc + t) * HDc;
#pragma unroll
        for (int n = 0; n < 4; ++n) rowp[n * 16 + lr] = (__bf16)acc[z][m][n][j];
      }
    }
  }

  // ---- epilogue: z=2 (V^T) via LDS bounce -> vt [B,H,HD,T] ----
  {
    const int bb2 = brow >> 11, t0b = brow & (Tc - 1);
    __bf16* tile_t = (__bf16*)Albuf;   // 32KB scratch; [64][136] = 17.4KB
#pragma unroll
    for (int h2 = 0; h2 < 2; ++h2) {
      __syncthreads();
      if (wc == h2) {
#pragma unroll
        for (int n = 0; n < 4; ++n)
#pragma unroll
          for (int m = 0; m < 2; ++m)
#pragma unroll
            for (int j = 0; j < 4; ++j)
              tile_t[(n * 16 + lr) * 136 + wr * 32 + m * 16 + lg * 4 + j] =
                  (__bf16)acc[2][m][n][j];
      }
      __syncthreads();
      const int hh2 = (bcol >> 6) + h2;
#pragma unroll
      for (int p = 0; p < 2; ++p) {
        const int r = p * 32 + (tid >> 4);
        const int c8 = (tid & 15) * 8;
        bf16x8 vvv = *(const bf16x8*)(tile_t + r * 136 + c8);
        *(bf16x8*)(vtout + (((size_t)bb2 * Hc + hh2) * HDc + r) * Tc + t0b + c8) = vvv;
      }
    }
  }
}

// ---------------- output projection GEMM: 128x64, swapped mfma, float4 stores -------
__launch_bounds__(256, 2)
__global__ void gemm_proj(const __bf16* __restrict__ A, const __bf16* __restrict__ W,
                          float* __restrict__ outf) {
  __shared__ __bf16 Alds[128 * 64];
  __shared__ __bf16 Blds[64 * 64];
  const int tid = threadIdx.x;
  const int lane = tid & 63, wid = tid >> 6;
  const int lr = lane & 15, lg = lane >> 4;
  const int lid = blockIdx.x + (int)gridDim.x * blockIdx.y;  // 512 blocks
  const int xcd = lid & 7, g = lid >> 3;
  const int brow = (xcd * 4 + (g & 3)) * 128;
  const int bcol = (g >> 2) * 64;
  f32x4 acc[2][4] = {};
  const char* Ag = (const char*)(A + (size_t)brow * Dc);
  const char* Bg = (const char*)(W + (size_t)bcol * Dc);
  const int r0 = tid >> 3;
  const int cb = (tid & 7) * 16;
  for (int k0 = 0; k0 < Dc; k0 += 64) {
#pragma unroll
    for (int i = 0; i < 4; ++i) {
      const int r = i * 32 + r0;
      const int ldsoff = (i * 256 + wid * 64) * 16;
      __builtin_amdgcn_global_load_lds(
          (gvoid_t*)(Ag + (size_t)r * (Dc * 2) + k0 * 2 + cb),
          (lvoid_t*)((char*)Alds + ldsoff), 16, 0, 0);
    }
#pragma unroll
    for (int i = 0; i < 2; ++i) {
      const int r = i * 32 + r0;
      const int ldsoff = (i * 256 + wid * 64) * 16;
      __builtin_amdgcn_global_load_lds(
          (gvoid_t*)(Bg + (size_t)r * (Dc * 2) + k0 * 2 + cb),
          (lvoid_t*)((char*)Blds + ldsoff), 16, 0, 0);
    }
    __syncthreads();
#pragma unroll
    for (int kk = 0; kk < 2; ++kk) {
      const int col = kk * 32 + lg * 8;
      bf16x8s af[2], bfv[4];
#pragma unroll
      for (int m = 0; m < 2; ++m)
        af[m] = *(const bf16x8s*)(Alds + (wid * 32 + m * 16 + lr) * 64 + col);
#pragma unroll
      for (int n = 0; n < 4; ++n)
        bfv[n] = *(const bf16x8s*)(Blds + (n * 16 + lr) * 64 + col);
#pragma unroll
      for (int m = 0; m < 2; ++m)
#pragma unroll
        for (int n = 0; n < 4; ++n)
          acc[m][n] = __builtin_amdgcn_mfma_f32_16x16x32_bf16(bfv[n], af[m], acc[m][n], 0, 0, 0);
    }
    __syncthreads();
  }
#pragma unroll
  for (int m = 0; m < 2; ++m) {
    const int gm = brow + wid * 32 + m * 16 + lr;
    float* rowp = outf + (size_t)gm * Dc + bcol;
#pragma unroll
    for (int n = 0; n < 4; ++n) {
      float4 fv;
      fv.x = acc[m][n][0]; fv.y = acc[m][n][1]; fv.z = acc[m][n][2]; fv.w = acc[m][n][3];
      *(float4*)(rowp + n * 16 + lg * 4) = fv;
    }
  }
}

// ---------------- causal flash attention (v12: 8 waves, q-tile 128, KVBLK 128) -----
// 512 blocks (32 bh x 16 q-tiles of 128 rows) x 512 thr. Wave (qq,kp): q-cols
// [qt*128+qq*32,+32) x kv-half [u*128+kp*64,+64). 2 blocks/CU (64KB LDS) = 16
// waves/CU, units/CU = 17 ({c,15-c} pairing). Static-max softmax, in-register P
// (cvt_pk+permlane), per-ct QK->SM->PV. V-LDS 256B rows -> swizzle key row&15.
// kp-partials additive (static max) -> one LDS combine at the end.
__launch_bounds__(512, 4)
__global__ void attn_kernel(const __bf16* __restrict__ Q, const __bf16* __restrict__ K,
                            const __bf16* __restrict__ Vt, __bf16* __restrict__ O) {
  __shared__ __bf16 Klds[2][128 * 64];   // [kv][hd] 128B rows, key kv&7
  __shared__ __bf16 Vlds[2][64 * 128];   // [hd][kv] 256B rows, key hd&15
  const int f = blockIdx.x;
  const int xcd = f & 7, g = f >> 3;     // 64 blocks per XCD = 4 bh x 16 q-tiles
  const int pass = g >> 4, g4 = g & 15;
  const int bh = xcd * 4 + pass;
  const int qt = ((pass >> 1) & 1) ? (15 - g4) : g4;  // CU pair {c,15-c} -> 17 units
  const int tid = threadIdx.x;
  const int lane = tid & 63, wid = tid >> 6;
  const int qq = wid >> 1, kp = wid & 1;       // wave's q-quarter / kv-half
  const int q31 = lane & 31, hh = lane >> 5;   // lane's q-col / split
  const int k3 = q31 & 7;                      // K row-XOR key (128B rows)
  const int v15 = q31 & 15;                    // V row-XOR key (256B rows)
  const __bf16* Qp = Q + (size_t)bh * Tc * HDc;
  const char* Kb = (const char*)(K + (size_t)bh * Tc * HDc);
  const char* Vb = (const char*)(Vt + (size_t)bh * HDc * Tc);

  const int units = qt + 1;

  // staging (8 waves cooperatively): K 2 instrs (64 rows each), V 2 instrs (32 rows)
  const int sr = tid >> 3;                               // K row within instr
  const int sxor = ((tid & 7) ^ (sr & 7)) << 4;          // K pre-swizzled src col
  const int vr = tid >> 4;                               // V row within instr
  const int vxor = ((tid & 15) ^ (vr & 15)) << 4;        // V pre-swizzled src col
  const char* vsrc = Vb + (size_t)vr * (Tc * 2) + vxor;

  const int q0w = qt * 128 + qq * 32;
  bf16x8s qf[4];
#pragma unroll
  for (int ks = 0; ks < 4; ++ks)
    qf[ks] = *(const bf16x8s*)(Qp + (q0w + q31) * HDc + ks * 16 + hh * 8);

  const int b = bh >> 4, h = bh & 15;

  f32x16 acc0 = {}, acc1 = {};
  float lsum = 0.f;

#define STAGE(IT, BUF)                                                                   \
  do {                                                                                   \
    _Pragma("unroll")                                                                    \
    for (int i_ = 0; i_ < 2; ++i_) {                                                     \
      __builtin_amdgcn_global_load_lds(                                                  \
          (gvoid_t*)(Kb + (size_t)((IT) * 128 + i_ * 64 + sr) * 128 + sxor),             \
          (lvoid_t*)((char*)Klds[BUF] + i_ * 8192 + wid * 1024), 16, 0, 0);              \
      __builtin_amdgcn_global_load_lds(                                                  \
          (gvoid_t*)(vsrc + (size_t)i_ * 32 * (Tc * 2) + (IT) * 256),                    \
          (lvoid_t*)((char*)Vlds[BUF] + i_ * 8192 + wid * 1024), 16, 0, 0);              \
    }                                                                                    \
  } while (0)

  STAGE(0, 0);
  asm volatile("s_waitcnt vmcnt(0)" ::: "memory");
  __builtin_amdgcn_sched_barrier(0);
  __builtin_amdgcn_s_barrier();
  __builtin_amdgcn_sched_barrier(0);

  for (int u = 0; u < units; ++u) {
    if (u + 1 < units) STAGE(u + 1, (u + 1) & 1);
    __builtin_amdgcn_sched_barrier(0);

    const bool last = (u == qt);
    if (!(last && kp == 1 && qq < 2)) {  // fully-masked waves skip (wave-uniform)
      const char* Kl = (const char*)Klds[u & 1];
      const char* Vl = (const char*)Vlds[u & 1];
      const bool fin = last && ((qq >> 1) == kp);   // partially-masked waves
      const int thr = q0w + q31 - u * 128 - kp * 64 - 4 * hh;  // mask: ct*32+n*8+j > thr

#pragma unroll
      for (int ct = 0; ct < 2; ++ct) {
        // ---- QK^T over 32 kv (swapped: D[kv][q], lane owns q-col) ----
        bf16x8s kf[4];
#pragma unroll
        for (int ks = 0; ks < 4; ++ks)
          kf[ks] = *(const bf16x8s*)(Kl + (kp * 64 + ct * 32 + q31) * 128 +
                                     (((2 * ks + hh) ^ k3) << 4));
        f32x16 z = {};
        __builtin_amdgcn_s_setprio(1);
#pragma unroll
        for (int ks = 0; ks < 4; ++ks)
          z = __builtin_amdgcn_mfma_f32_32x32x16_bf16(kf[ks], qf[ks], z, 0, 0, 0);
        __builtin_amdgcn_s_setprio(0);

        // ---- static-max softmax + pack ----
        unsigned w0[4], w1[4];
#pragma unroll
        for (int n = 0; n < 4; ++n) {
          float e[4];
#pragma unroll
          for (int j = 0; j < 4; ++j) {
            float ev = __builtin_amdgcn_exp2f(z[n * 4 + j]);
            if (fin && (ct * 32 + n * 8 + j > thr)) ev = 0.f;
            lsum += ev;
            e[j] = ev;
          }
          asm("v_cvt_pk_bf16_f32 %0, %1, %2" : "=v"(w0[n]) : "v"(e[0]), "v"(e[1]));
          asm("v_cvt_pk_bf16_f32 %0, %1, %2" : "=v"(w1[n]) : "v"(e[2]), "v"(e[3]));
        }

        // ---- assemble PV B-frags in registers (T12) ----
        bf16x8s pfr[2];
#pragma unroll
        for (int ks2 = 0; ks2 < 2; ++ks2) {
          unsigned a = w0[2 * ks2], bb2 = w0[2 * ks2 + 1];
          unsigned c = w1[2 * ks2], d = w1[2 * ks2 + 1];
          asm volatile("v_permlane32_swap_b32 %0, %1" : "+v"(a), "+v"(bb2));
          asm volatile("v_permlane32_swap_b32 %0, %1" : "+v"(c), "+v"(d));
          union { unsigned u[4]; bf16x8s v; } uu;
          uu.u[0] = a; uu.u[1] = c; uu.u[2] = bb2; uu.u[3] = d;
          pfr[ks2] = uu.v;
        }

        // ---- PV over these 32 kv: D[hd][q] ----
        __builtin_amdgcn_s_setprio(1);
#pragma unroll
        for (int ks2 = 0; ks2 < 2; ++ks2) {
          const int so = ((kp * 8 + ct * 4 + 2 * ks2 + hh) ^ v15) << 4;
          const bf16x8s va0 = *(const bf16x8s*)(Vl + q31 * 256 + so);
          const bf16x8s va1 = *(const bf16x8s*)(Vl + (32 + q31) * 256 + so);
          acc0 = __builtin_amdgcn_mfma_f32_32x32x16_bf16(va0, pfr[ks2], acc0, 0, 0, 0);
          acc1 = __builtin_amdgcn_mfma_f32_32x32x16_bf16(va1, pfr[ks2], acc1, 0, 0, 0);
        }
        __builtin_amdgcn_s_setprio(0);
      }
    }

    if (u + 1 < units) {
      asm volatile("s_waitcnt vmcnt(0)" ::: "memory");  // stage(u+1) landed
      __builtin_amdgcn_sched_barrier(0);
      __builtin_amdgcn_s_barrier();  // all waves done with buf[u&1]; buf[(u+1)&1] ready
      __builtin_amdgcn_sched_barrier(0);
    }
  }
#undef STAGE

  // ---- kp-pair combine (static max => additive), then finalize ----
  __syncthreads();  // all K/V reads done; buffers become scratch
  float* kscr = (float*)&Klds[0][0];   // 32KB: qq*2048 floats per pair
  float* lscr = (float*)&Vlds[0][0];
  if (kp == 1) {
#pragma unroll
    for (int i = 0; i < 16; ++i) {
      kscr[qq * 2048 + i * 64 + lane] = acc0[i];
      kscr[qq * 2048 + 1024 + i * 64 + lane] = acc1[i];
    }
    lscr[qq * 64 + lane] = lsum;
  }
  __syncthreads();
  if (kp == 0) {
#pragma unroll
    for (int i = 0; i < 16; ++i) {
      acc0[i] += kscr[qq * 2048 + i * 64 + lane];
      acc1[i] += kscr[qq * 2048 + 1024 + i * 64 + lane];
    }
    lsum += lscr[qq * 64 + lane];
    const float lt = lsum + __shfl_xor(lsum, 32);
    const float linv = 1.f / lt;
    const int t = q0w + q31;
    __bf16* dst = O + ((size_t)b * Tc + t) * Dc + h * HDc;
#pragma unroll
    for (int qd = 0; qd < 4; ++qd) {
      bf16x4 o0, o1;
#pragma unroll
      for (int j = 0; j < 4; ++j) {
        o0[j] = (__bf16)(acc0[qd * 4 + j] * linv);
        o1[j] = (__bf16)(acc1[qd * 4 + j] * linv);
      }
      *(bf16x4*)(dst + qd * 8 + hh * 4) = o0;
      *(bf16x4*)(dst + 32 + qd * 8 + hh * 4) = o1;
    }
  }
}

// ---------------- launch ----------------
extern "C" void kernel_launch(void* const* d_in, const int* in_sizes, int n_in,
                              void* d_out, int out_size, void* d_ws, size_t ws_size,
                              hipStream_t stream) {
  const float* x   = (const float*)d_in[0];
  const float* cbt = (const float*)d_in[1];
  const float* sbt = (const float*)d_in[2];
  const float* Wq  = (const float*)d_in[3];
  const float* Wk  = (const float*)d_in[4];
  const float* Wv  = (const float*)d_in[5];
  const float* Wp  = (const float*)d_in[6];
  float* out = (float*)d_out;
  char* ws = (char*)d_ws;
  __bf16* xb = (__bf16*)(ws);
  __bf16* wb = (__bf16*)(ws + (8u << 20));
  __bf16* qb = (__bf16*)(ws + (16u << 20));
  __bf16* vt = (__bf16*)(ws + (40u << 20));
  __bf16* ao = (__bf16*)(ws + (48u << 20));
  __bf16* kb = qb + (size_t)Mc * Dc;

  cvt_all<<<8192, 256, 0, stream>>>(x, Wq, Wk, Wv, Wp, xb, wb);
  gemm_qkv<<<dim3(8, 32), 512, 0, stream>>>(xb, wb, qb, vt, cbt, sbt);
  attn_kernel<<<512, 512, 0, stream>>>(qb, kb, vt, ao);
  gemm_proj<<<dim3(16, 32), 256, 0, stream>>>(ao, wb + 3u * (Dc * Dc), out);
}

// Round 18
// 92.851 us; speedup vs baseline: 1.0303x; 1.0303x over previous
//
#include <hip/hip_runtime.h>
#include <hip/hip_bf16.h>

typedef __attribute__((ext_vector_type(8))) short bf16x8s;   // 8 bf16 as shorts (MFMA frag)
typedef __attribute__((ext_vector_type(4))) float f32x4;
typedef __attribute__((ext_vector_type(16))) float f32x16;
typedef __attribute__((ext_vector_type(4))) __bf16 bf16x4;
typedef __attribute__((ext_vector_type(8))) __bf16 bf16x8;

typedef const __attribute__((address_space(1))) void gvoid_t;
typedef __attribute__((address_space(3))) void lvoid_t;

constexpr int Bc = 2, Tc = 2048, Dc = 1024, Hc = 16, HDc = 64;
constexpr int Mc = Bc * Tc;  // 4096

// ---------------- fused fp32 -> bf16 convert: x (4096 blocks) + 4 weights (4096) ----
__global__ void cvt_all(const float* __restrict__ x,
                        const float* __restrict__ wq, const float* __restrict__ wk,
                        const float* __restrict__ wv, const float* __restrict__ wp,
                        __bf16* __restrict__ xb, __bf16* __restrict__ wb) {
  const int bid = blockIdx.x;
  const float* src;
  __bf16* dst;
  int i;
  if (bid < 4096) {
    src = x; dst = xb; i = (bid * 256 + threadIdx.x) * 4;
  } else {
    const int r = bid - 4096;
    const int w = r >> 10;
    src = (w == 0) ? wq : (w == 1) ? wk : (w == 2) ? wv : wp;
    dst = wb + (size_t)w * (Dc * Dc);
    i = ((r & 1023) * 256 + threadIdx.x) * 4;
  }
  float4 v = *(const float4*)(src + i);
  bf16x4 o;
  o[0] = (__bf16)v.x; o[1] = (__bf16)v.y; o[2] = (__bf16)v.z; o[3] = (__bf16)v.w;
  *(bf16x4*)(dst + i) = o;
}

// ---------------- QKV GEMM (fused-z, v3): depth-2 pipeline, BK=32, 4 buffers -------
// 256 blocks x 512 thr (8 waves of 32x64); one block = 128x128 tile of Q,K,V.
// 32 K-steps; prologue stages 2 tiles; loop stages s+2 then vmcnt(8): tile s's
// loads span TWO compute phases (depth-2, T3/T4). One barrier/step (4-buffer reuse
// distance crosses >=2 barriers). LDS tiles row-pair packed: [64 rowpairs][128B],
// slot s8 = ((row&1)<<2 | kslot) ^ ((row>>1)&7) -> linear stage dest with
// inverse-swizzled source (rule 21); read slot = ((lr&1)<<2|lg)^(lr>>1): 2-way max.
__launch_bounds__(512, 2)
__global__ void gemm_qkv(const __bf16* __restrict__ A,
                         const __bf16* __restrict__ W,
                         __bf16* __restrict__ outb,
                         __bf16* __restrict__ vtout,
                         const float* __restrict__ cbt,
                         const float* __restrict__ sbt) {
  __shared__ __bf16 Abuf[4][128 * 32];       // 32KB
  __shared__ __bf16 Bbuf[4][3][128 * 32];    // 96KB
  const int tid = threadIdx.x;
  const int lane = tid & 63, wid = tid >> 6;
  const int wr = wid >> 1, wc = wid & 1;     // wave: rows [wr*32,+32), cols [wc*64,+64)
  const int lr = lane & 15, lg = lane >> 4;
  const int lid = blockIdx.x + 8 * blockIdx.y;   // grid (8,32)
  const int xcd = lid & 7, g = lid >> 3;
  const int brow = (xcd * 4 + (g & 3)) * 128;    // r16 map: 1MB A + 6MB B per XCD
  const int bcol = (g >> 2) * 128;

  f32x4 acc[3][2][4] = {};   // [z][m][n]

  const char* Ag = (const char*)(A + (size_t)brow * Dc);
  const char* Bg = (const char*)(W + (size_t)bcol * Dc);
  // stage source mapping: chunk c = tid -> r' = c>>3, s8 = c&7;
  // unswz = s8 ^ (r'&7); row = 2r' + (unswz>>2); kslot = unswz&3
  const int rp = tid >> 3;
  const int unswz = (tid & 7) ^ (rp & 7);
  const int srow = 2 * rp + (unswz >> 2);
  const int skoff = (unswz & 3) * 16;            // byte offset within the 32-k chunk

#define STAGE(K0, BUF)                                                                    \
  do {                                                                                    \
    __builtin_amdgcn_global_load_lds(                                                     \
        (gvoid_t*)(Ag + (size_t)srow * (Dc * 2) + (K0)*2 + skoff),                        \
        (lvoid_t*)((char*)Abuf[BUF] + tid * 16), 16, 0, 0);                               \
    _Pragma("unroll")                                                                     \
    for (int z_ = 0; z_ < 3; ++z_)                                                        \
      __builtin_amdgcn_global_load_lds(                                                   \
          (gvoid_t*)(Bg + (size_t)z_ * (Dc * Dc * 2) + (size_t)srow * (Dc * 2) +          \
                     (K0)*2 + skoff),                                                     \
          (lvoid_t*)((char*)Bbuf[BUF][z_] + tid * 16), 16, 0, 0);                         \
  } while (0)

  STAGE(0, 0);
  STAGE(32, 1);

  // read-side swizzle: slot = ((lr&1)<<2 | lg) ^ (lr>>1)
  const int swb = ((((lr & 1) << 2) | lg) ^ (lr >> 1)) << 4;
  const int lrh = lr >> 1;

  for (int s = 0; s < 32; ++s) {
    if (s + 2 < 32) {
      STAGE((s + 2) * 32, (s + 2) & 3);
      asm volatile("s_waitcnt vmcnt(8)" ::: "memory");   // tile s landed; s+1,s+2 in flight
    } else if (s + 1 < 32) {
      asm volatile("s_waitcnt vmcnt(4)" ::: "memory");
    } else {
      asm volatile("s_waitcnt vmcnt(0)" ::: "memory");
    }
    __builtin_amdgcn_sched_barrier(0);
    __builtin_amdgcn_s_barrier();        // tile s visible to all waves
    __builtin_amdgcn_sched_barrier(0);

    const char* Al = (const char*)Abuf[s & 3];
    const char* Bl0 = (const char*)Bbuf[s & 3][0];
    bf16x8s af[2];
#pragma unroll
    for (int m = 0; m < 2; ++m)
      af[m] = *(const bf16x8s*)(Al + (wr * 16 + m * 8 + lrh) * 128 + swb);
#pragma unroll
    for (int z = 0; z < 3; ++z) {
      const char* Bl = Bl0 + z * (128 * 32 * 2);
      bf16x8s bfv[4];
#pragma unroll
      for (int n = 0; n < 4; ++n)
        bfv[n] = *(const bf16x8s*)(Bl + (wc * 32 + n * 8 + lrh) * 128 + swb);
      __builtin_amdgcn_s_setprio(1);
#pragma unroll
      for (int m = 0; m < 2; ++m)
#pragma unroll
        for (int n = 0; n < 4; ++n)
          acc[z][m][n] =
              __builtin_amdgcn_mfma_f32_16x16x32_bf16(af[m], bfv[n], acc[z][m][n], 0, 0, 0);
      __builtin_amdgcn_s_setprio(0);
    }
  }
#undef STAGE

  // ---- epilogue: z=0 (Q: RoPE+scale), z=1 (K: RoPE) — scatter to [B,H,T,HD] ----
  const int h = (bcol >> 6) + wc;
#pragma unroll
  for (int z = 0; z < 2; ++z) {
    const float scl = (z == 0) ? 0.18033688011112042f : 1.0f;  // (1/8)*log2(e)
    __bf16* dst = outb + (size_t)z * ((size_t)Mc * Dc);
#pragma unroll
    for (int m = 0; m < 2; ++m) {
#pragma unroll
      for (int j = 0; j < 4; ++j) {
        const int gm = brow + wr * 32 + m * 16 + lg * 4 + j;
        const int bb = gm >> 11, t = gm & (Tc - 1);
        const float* cbase = cbt + (size_t)gm * HDc;
        const float* sbase = sbt + (size_t)gm * HDc;
#pragma unroll
        for (int n = 0; n < 2; ++n) {
          const int i = n * 16 + lr;
          const float c0 = cbase[i], s0 = sbase[i];   // cos[i+32]==cos[i]
          const float v0 = acc[z][m][n][j], v1 = acc[z][m][n + 2][j];
          acc[z][m][n][j]     = (v0 * c0 - v1 * s0) * scl;
          acc[z][m][n + 2][j] = (v1 * c0 + v0 * s0) * scl;
        }
        __bf16* rowp = dst + (((size_t)bb * Hc + h) * Tc + t) * HDc;
#pragma unroll
        for (int n = 0; n < 4; ++n) rowp[n * 16 + lr] = (__bf16)acc[z][m][n][j];
      }
    }
  }

  // ---- epilogue: z=2 (V^T) via LDS bounce -> vt [B,H,HD,T] ----
  {
    const int bb2 = brow >> 11, t0b = brow & (Tc - 1);
    __bf16* tile_t = (__bf16*)Abuf;   // 32KB scratch; [64][136] = 17.4KB
#pragma unroll
    for (int h2 = 0; h2 < 2; ++h2) {
      __syncthreads();
      if (wc == h2) {
#pragma unroll
        for (int n = 0; n < 4; ++n)
#pragma unroll
          for (int m = 0; m < 2; ++m)
#pragma unroll
            for (int j = 0; j < 4; ++j)
              tile_t[(n * 16 + lr) * 136 + wr * 32 + m * 16 + lg * 4 + j] =
                  (__bf16)acc[2][m][n][j];
      }
      __syncthreads();
      const int hh2 = (bcol >> 6) + h2;
#pragma unroll
      for (int p = 0; p < 2; ++p) {
        const int r = p * 32 + (tid >> 4);
        const int c8 = (tid & 15) * 8;
        bf16x8 vvv = *(const bf16x8*)(tile_t + r * 136 + c8);
        *(bf16x8*)(vtout + (((size_t)bb2 * Hc + hh2) * HDc + r) * Tc + t0b + c8) = vvv;
      }
    }
  }
}

// ---------------- output projection GEMM: 128x64, swapped mfma, float4 stores -------
__launch_bounds__(256, 2)
__global__ void gemm_proj(const __bf16* __restrict__ A, const __bf16* __restrict__ W,
                          float* __restrict__ outf) {
  __shared__ __bf16 Alds[128 * 64];
  __shared__ __bf16 Blds[64 * 64];
  const int tid = threadIdx.x;
  const int lane = tid & 63, wid = tid >> 6;
  const int lr = lane & 15, lg = lane >> 4;
  const int lid = blockIdx.x + (int)gridDim.x * blockIdx.y;  // 512 blocks
  const int xcd = lid & 7, g = lid >> 3;
  const int brow = (xcd * 4 + (g & 3)) * 128;
  const int bcol = (g >> 2) * 64;
  f32x4 acc[2][4] = {};
  const char* Ag = (const char*)(A + (size_t)brow * Dc);
  const char* Bg = (const char*)(W + (size_t)bcol * Dc);
  const int r0 = tid >> 3;
  const int cb = (tid & 7) * 16;
  for (int k0 = 0; k0 < Dc; k0 += 64) {
#pragma unroll
    for (int i = 0; i < 4; ++i) {
      const int r = i * 32 + r0;
      const int ldsoff = (i * 256 + wid * 64) * 16;
      __builtin_amdgcn_global_load_lds(
          (gvoid_t*)(Ag + (size_t)r * (Dc * 2) + k0 * 2 + cb),
          (lvoid_t*)((char*)Alds + ldsoff), 16, 0, 0);
    }
#pragma unroll
    for (int i = 0; i < 2; ++i) {
      const int r = i * 32 + r0;
      const int ldsoff = (i * 256 + wid * 64) * 16;
      __builtin_amdgcn_global_load_lds(
          (gvoid_t*)(Bg + (size_t)r * (Dc * 2) + k0 * 2 + cb),
          (lvoid_t*)((char*)Blds + ldsoff), 16, 0, 0);
    }
    __syncthreads();
#pragma unroll
    for (int kk = 0; kk < 2; ++kk) {
      const int col = kk * 32 + lg * 8;
      bf16x8s af[2], bfv[4];
#pragma unroll
      for (int m = 0; m < 2; ++m)
        af[m] = *(const bf16x8s*)(Alds + (wid * 32 + m * 16 + lr) * 64 + col);
#pragma unroll
      for (int n = 0; n < 4; ++n)
        bfv[n] = *(const bf16x8s*)(Blds + (n * 16 + lr) * 64 + col);
#pragma unroll
      for (int m = 0; m < 2; ++m)
#pragma unroll
        for (int n = 0; n < 4; ++n)
          acc[m][n] = __builtin_amdgcn_mfma_f32_16x16x32_bf16(bfv[n], af[m], acc[m][n], 0, 0, 0);
    }
    __syncthreads();
  }
#pragma unroll
  for (int m = 0; m < 2; ++m) {
    const int gm = brow + wid * 32 + m * 16 + lr;
    float* rowp = outf + (size_t)gm * Dc + bcol;
#pragma unroll
    for (int n = 0; n < 4; ++n) {
      float4 fv;
      fv.x = acc[m][n][0]; fv.y = acc[m][n][1]; fv.z = acc[m][n][2]; fv.w = acc[m][n][3];
      *(float4*)(rowp + n * 16 + lg * 4) = fv;
    }
  }
}

// ---------------- causal flash attention (v12: 8 waves, q-tile 128, KVBLK 128) -----
__launch_bounds__(512, 4)
__global__ void attn_kernel(const __bf16* __restrict__ Q, const __bf16* __restrict__ K,
                            const __bf16* __restrict__ Vt, __bf16* __restrict__ O) {
  __shared__ __bf16 Klds[2][128 * 64];   // [kv][hd] 128B rows, key kv&7
  __shared__ __bf16 Vlds[2][64 * 128];   // [hd][kv] 256B rows, key hd&15
  const int f = blockIdx.x;
  const int xcd = f & 7, g = f >> 3;     // 64 blocks per XCD = 4 bh x 16 q-tiles
  const int pass = g >> 4, g4 = g & 15;
  const int bh = xcd * 4 + pass;
  const int qt = ((pass >> 1) & 1) ? (15 - g4) : g4;  // CU pair {c,15-c} -> 17 units
  const int tid = threadIdx.x;
  const int lane = tid & 63, wid = tid >> 6;
  const int qq = wid >> 1, kp = wid & 1;       // wave's q-quarter / kv-half
  const int q31 = lane & 31, hh = lane >> 5;   // lane's q-col / split
  const int k3 = q31 & 7;                      // K row-XOR key (128B rows)
  const int v15 = q31 & 15;                    // V row-XOR key (256B rows)
  const __bf16* Qp = Q + (size_t)bh * Tc * HDc;
  const char* Kb = (const char*)(K + (size_t)bh * Tc * HDc);
  const char* Vb = (const char*)(Vt + (size_t)bh * HDc * Tc);

  const int units = qt + 1;

  const int sr = tid >> 3;                               // K row within instr
  const int sxor = ((tid & 7) ^ (sr & 7)) << 4;          // K pre-swizzled src col
  const int vr = tid >> 4;                               // V row within instr
  const int vxor = ((tid & 15) ^ (vr & 15)) << 4;        // V pre-swizzled src col
  const char* vsrc = Vb + (size_t)vr * (Tc * 2) + vxor;

  const int q0w = qt * 128 + qq * 32;
  bf16x8s qf[4];
#pragma unroll
  for (int ks = 0; ks < 4; ++ks)
    qf[ks] = *(const bf16x8s*)(Qp + (q0w + q31) * HDc + ks * 16 + hh * 8);

  const int b = bh >> 4, h = bh & 15;

  f32x16 acc0 = {}, acc1 = {};
  float lsum = 0.f;

#define STAGE(IT, BUF)                                                                   \
  do {                                                                                   \
    _Pragma("unroll")                                                                    \
    for (int i_ = 0; i_ < 2; ++i_) {                                                     \
      __builtin_amdgcn_global_load_lds(                                                  \
          (gvoid_t*)(Kb + (size_t)((IT) * 128 + i_ * 64 + sr) * 128 + sxor),             \
          (lvoid_t*)((char*)Klds[BUF] + i_ * 8192 + wid * 1024), 16, 0, 0);              \
      __builtin_amdgcn_global_load_lds(                                                  \
          (gvoid_t*)(vsrc + (size_t)i_ * 32 * (Tc * 2) + (IT) * 256),                    \
          (lvoid_t*)((char*)Vlds[BUF] + i_ * 8192 + wid * 1024), 16, 0, 0);              \
    }                                                                                    \
  } while (0)

  STAGE(0, 0);
  asm volatile("s_waitcnt vmcnt(0)" ::: "memory");
  __builtin_amdgcn_sched_barrier(0);
  __builtin_amdgcn_s_barrier();
  __builtin_amdgcn_sched_barrier(0);

  for (int u = 0; u < units; ++u) {
    if (u + 1 < units) STAGE(u + 1, (u + 1) & 1);
    __builtin_amdgcn_sched_barrier(0);

    const bool last = (u == qt);
    if (!(last && kp == 1 && qq < 2)) {  // fully-masked waves skip (wave-uniform)
      const char* Kl = (const char*)Klds[u & 1];
      const char* Vl = (const char*)Vlds[u & 1];
      const bool fin = last && ((qq >> 1) == kp);   // partially-masked waves
      const int thr = q0w + q31 - u * 128 - kp * 64 - 4 * hh;  // mask: ct*32+n*8+j > thr

#pragma unroll
      for (int ct = 0; ct < 2; ++ct) {
        bf16x8s kf[4];
#pragma unroll
        for (int ks = 0; ks < 4; ++ks)
          kf[ks] = *(const bf16x8s*)(Kl + (kp * 64 + ct * 32 + q31) * 128 +
                                     (((2 * ks + hh) ^ k3) << 4));
        f32x16 z = {};
        __builtin_amdgcn_s_setprio(1);
#pragma unroll
        for (int ks = 0; ks < 4; ++ks)
          z = __builtin_amdgcn_mfma_f32_32x32x16_bf16(kf[ks], qf[ks], z, 0, 0, 0);
        __builtin_amdgcn_s_setprio(0);

        unsigned w0[4], w1[4];
#pragma unroll
        for (int n = 0; n < 4; ++n) {
          float e[4];
#pragma unroll
          for (int j = 0; j < 4; ++j) {
            float ev = __builtin_amdgcn_exp2f(z[n * 4 + j]);
            if (fin && (ct * 32 + n * 8 + j > thr)) ev = 0.f;
            lsum += ev;
            e[j] = ev;
          }
          asm("v_cvt_pk_bf16_f32 %0, %1, %2" : "=v"(w0[n]) : "v"(e[0]), "v"(e[1]));
          asm("v_cvt_pk_bf16_f32 %0, %1, %2" : "=v"(w1[n]) : "v"(e[2]), "v"(e[3]));
        }

        bf16x8s pfr[2];
#pragma unroll
        for (int ks2 = 0; ks2 < 2; ++ks2) {
          unsigned a = w0[2 * ks2], bb2 = w0[2 * ks2 + 1];
          unsigned c = w1[2 * ks2], d = w1[2 * ks2 + 1];
          asm volatile("v_permlane32_swap_b32 %0, %1" : "+v"(a), "+v"(bb2));
          asm volatile("v_permlane32_swap_b32 %0, %1" : "+v"(c), "+v"(d));
          union { unsigned u[4]; bf16x8s v; } uu;
          uu.u[0] = a; uu.u[1] = c; uu.u[2] = bb2; uu.u[3] = d;
          pfr[ks2] = uu.v;
        }

        __builtin_amdgcn_s_setprio(1);
#pragma unroll
        for (int ks2 = 0; ks2 < 2; ++ks2) {
          const int so = ((kp * 8 + ct * 4 + 2 * ks2 + hh) ^ v15) << 4;
          const bf16x8s va0 = *(const bf16x8s*)(Vl + q31 * 256 + so);
          const bf16x8s va1 = *(const bf16x8s*)(Vl + (32 + q31) * 256 + so);
          acc0 = __builtin_amdgcn_mfma_f32_32x32x16_bf16(va0, pfr[ks2], acc0, 0, 0, 0);
          acc1 = __builtin_amdgcn_mfma_f32_32x32x16_bf16(va1, pfr[ks2], acc1, 0, 0, 0);
        }
        __builtin_amdgcn_s_setprio(0);
      }
    }

    if (u + 1 < units) {
      asm volatile("s_waitcnt vmcnt(0)" ::: "memory");  // stage(u+1) landed
      __builtin_amdgcn_sched_barrier(0);
      __builtin_amdgcn_s_barrier();  // all waves done with buf[u&1]; buf[(u+1)&1] ready
      __builtin_amdgcn_sched_barrier(0);
    }
  }
#undef STAGE

  // ---- kp-pair combine (static max => additive), then finalize ----
  __syncthreads();  // all K/V reads done; buffers become scratch
  float* kscr = (float*)&Klds[0][0];   // 32KB: qq*2048 floats per pair
  float* lscr = (float*)&Vlds[0][0];
  if (kp == 1) {
#pragma unroll
    for (int i = 0; i < 16; ++i) {
      kscr[qq * 2048 + i * 64 + lane] = acc0[i];
      kscr[qq * 2048 + 1024 + i * 64 + lane] = acc1[i];
    }
    lscr[qq * 64 + lane] = lsum;
  }
  __syncthreads();
  if (kp == 0) {
#pragma unroll
    for (int i = 0; i < 16; ++i) {
      acc0[i] += kscr[qq * 2048 + i * 64 + lane];
      acc1[i] += kscr[qq * 2048 + 1024 + i * 64 + lane];
    }
    lsum += lscr[qq * 64 + lane];
    const float lt = lsum + __shfl_xor(lsum, 32);
    const float linv = 1.f / lt;
    const int t = q0w + q31;
    __bf16* dst = O + ((size_t)b * Tc + t) * Dc + h * HDc;
#pragma unroll
    for (int qd = 0; qd < 4; ++qd) {
      bf16x4 o0, o1;
#pragma unroll
      for (int j = 0; j < 4; ++j) {
        o0[j] = (__bf16)(acc0[qd * 4 + j] * linv);
        o1[j] = (__bf16)(acc1[qd * 4 + j] * linv);
      }
      *(bf16x4*)(dst + qd * 8 + hh * 4) = o0;
      *(bf16x4*)(dst + 32 + qd * 8 + hh * 4) = o1;
    }
  }
}

// ---------------- launch ----------------
extern "C" void kernel_launch(void* const* d_in, const int* in_sizes, int n_in,
                              void* d_out, int out_size, void* d_ws, size_t ws_size,
                              hipStream_t stream) {
  const float* x   = (const float*)d_in[0];
  const float* cbt = (const float*)d_in[1];
  const float* sbt = (const float*)d_in[2];
  const float* Wq  = (const float*)d_in[3];
  const float* Wk  = (const float*)d_in[4];
  const float* Wv  = (const float*)d_in[5];
  const float* Wp  = (const float*)d_in[6];
  float* out = (float*)d_out;
  char* ws = (char*)d_ws;
  __bf16* xb = (__bf16*)(ws);
  __bf16* wb = (__bf16*)(ws + (8u << 20));
  __bf16* qb = (__bf16*)(ws + (16u << 20));
  __bf16* vt = (__bf16*)(ws + (40u << 20));
  __bf16* ao = (__bf16*)(ws + (48u << 20));
  __bf16* kb = qb + (size_t)Mc * Dc;

  cvt_all<<<8192, 256, 0, stream>>>(x, Wq, Wk, Wv, Wp, xb, wb);
  gemm_qkv<<<dim3(8, 32), 512, 0, stream>>>(xb, wb, qb, vt, cbt, sbt);
  attn_kernel<<<512, 512, 0, stream>>>(qb, kb, vt, ao);
  gemm_proj<<<dim3(16, 32), 256, 0, stream>>>(ao, wb + 3u * (Dc * Dc), out);
}